// Round 9
// baseline (3388.636 us; speedup 1.0000x reference)
//
#include <hip/hip_runtime.h>
#include <hip/hip_bf16.h>

typedef __attribute__((ext_vector_type(4)))  int   i32x4;
typedef __attribute__((ext_vector_type(8)))  int   i32x8;
typedef __attribute__((ext_vector_type(16))) float f32x16;

#define NEG_L2K (-0.025952563241307517f)  // -log2(10000)/512

#define VMW(N) asm volatile("s_waitcnt vmcnt(" #N ")" ::: "memory")
#define LKW0() asm volatile("s_waitcnt lgkmcnt(0)" ::: "memory")
#define SCHB() __builtin_amdgcn_sched_barrier(0)
#define SBAR() __builtin_amdgcn_s_barrier()

#define AS1 __attribute__((address_space(1)))
#define AS3 __attribute__((address_space(3)))

__device__ __forceinline__ unsigned int pk4_fp8(float a, float b, float c, float d) {
    unsigned int v = __builtin_amdgcn_cvt_pk_fp8_f32(a, b, 0, false);
    v = __builtin_amdgcn_cvt_pk_fp8_f32(c, d, v, true);
    return v;
}

// ---------------- Kernel 1: X fp32 -> fp8, fragment-major, BM=128 tiles ----
// Tile (mtile,kt) = 8192 B at (mtile*32+kt)*8192.  Chunk s*64+lane (16 B):
// s = mf*2+rd; bytes = fp8(X[mtile*128+mf*32+(lane&31)][kt*64+(lane>>5)*32+rd*16 ..+16])
__global__ __launch_bounds__(256) void prep_x_kernel(const float* __restrict__ X,
                                                     unsigned char* __restrict__ Xf,
                                                     float* __restrict__ A) {
    int g = blockIdx.x * 256 + threadIdx.x;   // 0 .. 2^21-1
    if (g < 8192) A[g] = 0.0f;
    int tileid = g >> 9;       // 0..4095
    int mtile  = tileid >> 5;  // 0..127
    int kt     = tileid & 31;
    int c      = g & 511;
    int s      = c >> 6;       // 0..7 = mf*2+rd
    int lane   = c & 63;
    int row  = mtile * 128 + (s >> 1) * 32 + (lane & 31);
    int kcol = kt * 64 + (lane >> 5) * 32 + (s & 1) * 16;
    const float* src = X + (size_t)row * 2048 + kcol;
    float4 f0 = *(const float4*)(src);
    float4 f1 = *(const float4*)(src + 4);
    float4 f2 = *(const float4*)(src + 8);
    float4 f3 = *(const float4*)(src + 12);
    uint4 o;
    o.x = pk4_fp8(f0.x, f0.y, f0.z, f0.w);
    o.y = pk4_fp8(f1.x, f1.y, f1.z, f1.w);
    o.z = pk4_fp8(f2.x, f2.y, f2.z, f2.w);
    o.w = pk4_fp8(f3.x, f3.y, f3.z, f3.w);
    *(uint4*)(Xf + (size_t)g * 16) = o;
}

// ---------------- Kernel 2: W fp32 -> fp8 (x16 pre-scale) frag-major -------
// (verified in R7 — unchanged)  Out tile (ntile,kt,KV) = 8 KB at
// ((ntile*32+kt)*2+KV)*8192; chunk (wc*2+rd)*64+lane holds
// W[kt*64+(lane>>5)*32+rd*16 ..+16][ntile*128+wc*32+(lane&31)]*16
__global__ __launch_bounds__(256) void prep_w_kernel(const float* __restrict__ W,
                                                     unsigned char* __restrict__ Wf) {
    __shared__ unsigned char t[64][72];
    int f0 = blockIdx.x * 64;   // along 4096 (f)
    int k0 = blockIdx.y * 64;   // along 2048 (k)
    int tx = threadIdx.x & 63;
    int ty = threadIdx.x >> 6;
    for (int r = ty; r < 64; r += 4) {
        float w = W[(size_t)(k0 + r) * 4096 + f0 + tx] * 16.0f;
        t[r][tx] = (unsigned char)(__builtin_amdgcn_cvt_pk_fp8_f32(w, w, 0, false) & 0xFF);
    }
    __syncthreads();
    int c   = threadIdx.x;
    int il  = c & 31;
    int lh  = (c >> 5) & 1;
    int rd  = (c >> 6) & 1;
    int wcl = c >> 7;
    int col_l = wcl * 32 + il;          // 0..63 within block
    int kl    = lh * 32 + rd * 16;
    int fh    = f0 & 2047;
    int KV    = f0 >> 11;
    int ntile = fh >> 7;
    int wcg   = ((fh >> 5) & 2) + wcl;
    union { unsigned char b[16]; uint4 v; } ob;
    #pragma unroll
    for (int b = 0; b < 16; ++b) ob.b[b] = t[kl + b][col_l];
    size_t base = ((((size_t)ntile * 32 + blockIdx.y) * 2 + KV) << 13)
                + (size_t)(((wcg * 2 + rd) * 64 + lh * 32 + il) << 4);
    *(uint4*)(Wf + base) = ob.v;
}

// ---------------- Kernel 3: fused fp8 GEMM + rotary + cos*cos + reduce ----
// MX-fp8 mfma_scale 32x32x64.  4 waves/block, BM=128, LDS 32 KB/block
// (A dbuf 16K + K 8K + V 8K single-buffered) -> 5 blocks/CU.  Per K-step:
// wait+SBAR, reg-read all fragments, lgkmcnt(0)+SBAR, stage t+1, MFMA.
__global__ __launch_bounds__(256, 5) void gemm_acos_kernel(
    const unsigned char* __restrict__ Xf,
    const unsigned char* __restrict__ Wf,
    const float* __restrict__ bias,
    float* __restrict__ A)
{
    __shared__ __align__(16) unsigned char Als[2][8192];
    __shared__ __align__(16) unsigned char Kls[8192];
    __shared__ __align__(16) unsigned char Vls[8192];

    const int tid  = threadIdx.x;
    const int lane = tid & 63;
    const int wc   = tid >> 6;    // 0..3  col quarter (32 cols)
    const int l31  = lane & 31;
    const int lh   = lane >> 5;

    // T1: bijective XCD swizzle, grid 2048 = 128 mtiles x 16 ntiles
    const int orig  = blockIdx.x;
    const int wg    = (orig & 7) * 256 + (orig >> 3);
    const int mtile = wg & 127;
    const int ntile = wg >> 7;
    const int row0  = mtile * 128;
    const int n0    = ntile * 128;

    const unsigned char* XfT = Xf + ((size_t)(mtile * 32) << 13);
    const unsigned char* WfT = Wf + ((size_t)(ntile * 32) << 14);

    f32x16 accK[4] = {};
    f32x16 accV[4] = {};

    const int abase = lane * 16;                 // + mf*2048 + rd*1024
    const int bbase = (wc * 128 + lane) * 16;    // + rd*1024

    // stage one K-tile (A 8 KB -> Als[NB], K 8 KB, V 8 KB) : 6 loads/thread
    #define STAGE(T, NB)                                                                    \
        do {                                                                                \
            const unsigned char* ga = XfT + ((size_t)(T) << 13);                            \
            const unsigned char* gw = WfT + ((size_t)(T) << 14);                            \
            __builtin_amdgcn_global_load_lds((const AS1 void*)(ga + tid * 16),              \
                (AS3 void*)(Als[NB] + tid * 16), 16, 0, 0);                                 \
            __builtin_amdgcn_global_load_lds((const AS1 void*)(ga + 4096 + tid * 16),       \
                (AS3 void*)(Als[NB] + 4096 + tid * 16), 16, 0, 0);                          \
            __builtin_amdgcn_global_load_lds((const AS1 void*)(gw + tid * 16),              \
                (AS3 void*)(Kls + tid * 16), 16, 0, 0);                                     \
            __builtin_amdgcn_global_load_lds((const AS1 void*)(gw + 4096 + tid * 16),       \
                (AS3 void*)(Kls + 4096 + tid * 16), 16, 0, 0);                              \
            __builtin_amdgcn_global_load_lds((const AS1 void*)(gw + 8192 + tid * 16),       \
                (AS3 void*)(Vls + tid * 16), 16, 0, 0);                                     \
            __builtin_amdgcn_global_load_lds((const AS1 void*)(gw + 12288 + tid * 16),      \
                (AS3 void*)(Vls + 4096 + tid * 16), 16, 0, 0);                              \
        } while (0)

    STAGE(0, 0);

    #pragma unroll 1
    for (int it = 0; it < 16; ++it) {
        #pragma unroll
        for (int sub = 0; sub < 2; ++sub) {
            const int t = it * 2 + sub;
            const bool last = (t == 31);
            const unsigned char* As = Als[sub];

            // ---- tile t's 6 loads (issued at step t-1) must have landed
            VMW(0); SCHB();
            SBAR();

            // ---- read ALL fragments for this K-step into registers
            i32x8 a8[4], bk8, bv8;
            #pragma unroll
            for (int mf = 0; mf < 4; ++mf) {
                i32x4 lo = *(const i32x4*)(As + abase + mf * 2048);
                i32x4 hi = *(const i32x4*)(As + abase + mf * 2048 + 1024);
                a8[mf] = __builtin_shufflevector(lo, hi, 0, 1, 2, 3, 4, 5, 6, 7);
            }
            {
                i32x4 lo = *(const i32x4*)(Kls + bbase);
                i32x4 hi = *(const i32x4*)(Kls + bbase + 1024);
                bk8 = __builtin_shufflevector(lo, hi, 0, 1, 2, 3, 4, 5, 6, 7);
                lo = *(const i32x4*)(Vls + bbase);
                hi = *(const i32x4*)(Vls + bbase + 1024);
                bv8 = __builtin_shufflevector(lo, hi, 0, 1, 2, 3, 4, 5, 6, 7);
            }
            LKW0(); SCHB();            // reads complete before K/V overwrite
            SBAR();

            // ---- stage tile t+1 (A -> other buf; K/V -> same bufs)
            if (!last) STAGE(t + 1, sub ^ 1);

            // ---- MFMA clusters (pure register)
            __builtin_amdgcn_s_setprio(1);
            #pragma unroll
            for (int mf = 0; mf < 4; ++mf)
                accK[mf] = __builtin_amdgcn_mfma_scale_f32_32x32x64_f8f6f4(
                    a8[mf], bk8, accK[mf], 0, 0, 0, 0x7F7F7F7F, 0, 0x7B7B7B7B);
            __builtin_amdgcn_s_setprio(0);
            __builtin_amdgcn_s_setprio(1);
            #pragma unroll
            for (int mf = 0; mf < 4; ++mf)
                accV[mf] = __builtin_amdgcn_mfma_scale_f32_32x32x64_f8f6f4(
                    a8[mf], bv8, accV[mf], 0, 0, 0, 0x7F7F7F7F, 0, 0x7B7B7B7B);
            __builtin_amdgcn_s_setprio(0);
        }
    }

    // ---- epilogue: bias, rotary, cos*cos, reduce over rows, atomicAdd
    // C/D (32x32): col = lane&31, row = (reg&3) + 8*(reg>>2) + 4*lh
    const int batch = row0 >> 12;
    const int c     = n0 + wc * 32 + l31;
    const float bK  = bias[c];
    const float bV  = bias[c + 2048];
    const bool rot  = (c < 1024);
    const float invf = exp2f((float)(c >> 1) * NEG_L2K);
    const float sgn  = (c & 1) ? 1.0f : -1.0f;
    const int sbase  = (row0 & 4095) + 4 * lh;

    float colsum = 0.0f;
    #pragma unroll
    for (int mf = 0; mf < 4; ++mf) {
        #pragma unroll
        for (int r = 0; r < 16; ++r) {
            const int srow = sbase + mf * 32 + (r & 3) + 8 * (r >> 2);
            float kv = accK[mf][r] + bK;
            float vv = accV[mf][r] + bV;
            float pk = __shfl_xor(kv, 1);
            float pv = __shfl_xor(vv, 1);
            float kr = kv, vr = vv;
            if (rot) {
                float sn, cs;
                __sincosf((float)srow * invf, &sn, &cs);
                float tt = sgn * sn;
                kr = kv * cs + pk * tt;
                vr = vv * cs + pv * tt;
            }
            colsum += __cosf(kr) * __cosf(vr);
        }
    }
    colsum += __shfl_xor(colsum, 32);
    if (lane < 32)
        atomicAdd(&A[batch * 2048 + c], colsum);
}

// ---------------- Kernel 4: out = (0.5*A + 0.5) * X --------------------
__global__ void scale_out_kernel(const float* __restrict__ X,
                                 const float* __restrict__ A,
                                 float* __restrict__ out, int n4) {
    int gid = blockIdx.x * blockDim.x + threadIdx.x;
    int stride = gridDim.x * blockDim.x;
    for (int i = gid; i < n4; i += stride) {
        int e0 = i * 4;
        int b  = e0 >> 23;        // S*D = 2^23
        int d  = e0 & 2047;
        float4 a4 = *(const float4*)(A + b * 2048 + d);
        float4 x4 = ((const float4*)X)[i];
        float4 o;
        o.x = (0.5f * a4.x + 0.5f) * x4.x;
        o.y = (0.5f * a4.y + 0.5f) * x4.y;
        o.z = (0.5f * a4.z + 0.5f) * x4.z;
        o.w = (0.5f * a4.w + 0.5f) * x4.w;
        ((float4*)out)[i] = o;
    }
}

extern "C" void kernel_launch(void* const* d_in, const int* in_sizes, int n_in,
                              void* d_out, int out_size, void* d_ws, size_t ws_size,
                              hipStream_t stream) {
    const float* X    = (const float*)d_in[0];   // [4][4096][2048]
    const float* W    = (const float*)d_in[1];   // [2048][4096]
    const float* bias = (const float*)d_in[2];   // [4096]
    float* out = (float*)d_out;

    const size_t szA  = 32768;                        // 4*2048*4 (padded)
    const size_t szWf = (size_t)4096 * 2048;          // 8.4 MB fp8
    const size_t szXf = (size_t)16384 * 2048;         // 33.5 MB fp8

    char* ws = (char*)d_ws;
    float* A = (float*)ws;                            // assume ws >= 32 KB
    unsigned char* Wf;
    unsigned char* Xf;
    if (ws_size >= szA + szWf + szXf) {
        Wf = (unsigned char*)(ws + szA);
        Xf = (unsigned char*)(ws + szA + szWf);
    } else if (ws_size >= szA + szWf) {
        Wf = (unsigned char*)(ws + szA);
        Xf = (unsigned char*)d_out;                   // scratch; rewritten by kernel 4
    } else {
        Xf = (unsigned char*)d_out;
        Wf = (unsigned char*)d_out + szXf;            // 42 MB <= 134 MB
    }

    prep_x_kernel<<<8192, 256, 0, stream>>>(X, Xf, A);
    prep_w_kernel<<<dim3(64, 32), 256, 0, stream>>>(W, Wf);
    gemm_acos_kernel<<<2048, 256, 0, stream>>>(Xf, Wf, bias, A);
    scale_out_kernel<<<2048, 256, 0, stream>>>(X, A, out, 16384 * 2048 / 4);
}

// Round 10
// 269.907 us; speedup vs baseline: 12.5548x; 12.5548x over previous
//
#include <hip/hip_runtime.h>
#include <hip/hip_bf16.h>

typedef __attribute__((ext_vector_type(4)))  int   i32x4;
typedef __attribute__((ext_vector_type(8)))  int   i32x8;
typedef __attribute__((ext_vector_type(16))) float f32x16;

#define NEG_L2K (-0.025952563241307517f)  // -log2(10000)/512

#define VMW(N) asm volatile("s_waitcnt vmcnt(" #N ")" ::: "memory")
#define SCHB() __builtin_amdgcn_sched_barrier(0)
#define SBAR() __builtin_amdgcn_s_barrier()

#define AS1 __attribute__((address_space(1)))
#define AS3 __attribute__((address_space(3)))

__device__ __forceinline__ unsigned int pk4_fp8(float a, float b, float c, float d) {
    unsigned int v = __builtin_amdgcn_cvt_pk_fp8_f32(a, b, 0, false);
    v = __builtin_amdgcn_cvt_pk_fp8_f32(c, d, v, true);
    return v;
}

// ---------------- Kernel 1: X fp32 -> fp8, fragment-major, BM=128 tiles ----
// (verified R8 — unchanged)
__global__ __launch_bounds__(256) void prep_x_kernel(const float* __restrict__ X,
                                                     unsigned char* __restrict__ Xf,
                                                     float* __restrict__ A) {
    int g = blockIdx.x * 256 + threadIdx.x;   // 0 .. 2^21-1
    if (g < 8192) A[g] = 0.0f;
    int tileid = g >> 9;       // 0..4095
    int mtile  = tileid >> 5;  // 0..127
    int kt     = tileid & 31;
    int c      = g & 511;
    int s      = c >> 6;       // 0..7 = mf*2+rd
    int lane   = c & 63;
    int row  = mtile * 128 + (s >> 1) * 32 + (lane & 31);
    int kcol = kt * 64 + (lane >> 5) * 32 + (s & 1) * 16;
    const float* src = X + (size_t)row * 2048 + kcol;
    float4 f0 = *(const float4*)(src);
    float4 f1 = *(const float4*)(src + 4);
    float4 f2 = *(const float4*)(src + 8);
    float4 f3 = *(const float4*)(src + 12);
    uint4 o;
    o.x = pk4_fp8(f0.x, f0.y, f0.z, f0.w);
    o.y = pk4_fp8(f1.x, f1.y, f1.z, f1.w);
    o.z = pk4_fp8(f2.x, f2.y, f2.z, f2.w);
    o.w = pk4_fp8(f3.x, f3.y, f3.z, f3.w);
    *(uint4*)(Xf + (size_t)g * 16) = o;
}

// ---------------- Kernel 2: W fp32 -> fp8 (x16 pre-scale) frag-major -------
// (verified R7/R8 — unchanged).  Note: each 8 KB tile's 4 KB halves are the
// two 64-col sub-tiles (wcg>=2 at +4096), so BN=64 blocks read +(n&1)*4096.
__global__ __launch_bounds__(256) void prep_w_kernel(const float* __restrict__ W,
                                                     unsigned char* __restrict__ Wf) {
    __shared__ unsigned char t[64][72];
    int f0 = blockIdx.x * 64;   // along 4096 (f)
    int k0 = blockIdx.y * 64;   // along 2048 (k)
    int tx = threadIdx.x & 63;
    int ty = threadIdx.x >> 6;
    for (int r = ty; r < 64; r += 4) {
        float w = W[(size_t)(k0 + r) * 4096 + f0 + tx] * 16.0f;
        t[r][tx] = (unsigned char)(__builtin_amdgcn_cvt_pk_fp8_f32(w, w, 0, false) & 0xFF);
    }
    __syncthreads();
    int c   = threadIdx.x;
    int il  = c & 31;
    int lh  = (c >> 5) & 1;
    int rd  = (c >> 6) & 1;
    int wcl = c >> 7;
    int col_l = wcl * 32 + il;          // 0..63 within block
    int kl    = lh * 32 + rd * 16;
    int fh    = f0 & 2047;
    int KV    = f0 >> 11;
    int ntile = fh >> 7;
    int wcg   = ((fh >> 5) & 2) + wcl;
    union { unsigned char b[16]; uint4 v; } ob;
    #pragma unroll
    for (int b = 0; b < 16; ++b) ob.b[b] = t[kl + b][col_l];
    size_t base = ((((size_t)ntile * 32 + blockIdx.y) * 2 + KV) << 13)
                + (size_t)(((wcg * 2 + rd) * 64 + lh * 32 + il) << 4);
    *(uint4*)(Wf + base) = ob.v;
}

// ---------------- Kernel 3: fused fp8 GEMM + rotary + cos*cos + reduce ----
// BM=128 x BN=64(K)+64(V).  4 waves = (kv, col-half): each computes 128x32
// of K or V -> acc only 64 regs -> ~140 regs/wave -> 3 waves/SIMD.
// Epilogue: K-waves write cos(Krot) to LDS; V-waves multiply+reduce.
__global__ __launch_bounds__(256, 3) void gemm_acos_kernel(
    const unsigned char* __restrict__ Xf,
    const unsigned char* __restrict__ Wf,
    const float* __restrict__ bias,
    float* __restrict__ A)
{
    __shared__ __align__(16) unsigned char SMEM[32768];
    unsigned char* Als0 = SMEM;            // [2][8192]
    unsigned char* Kls0 = SMEM + 16384;    // [2][4096]
    unsigned char* Vls0 = SMEM + 24576;    // [2][4096]

    const int tid  = threadIdx.x;
    const int lane = tid & 63;
    const int wid  = tid >> 6;    // 0..3
    const int kv   = wid >> 1;    // 0 = K-wave, 1 = V-wave
    const int ch   = wid & 1;     // col half (32 cols)
    const int l31  = lane & 31;
    const int lh   = lane >> 5;

    // T1: bijective XCD swizzle, grid 4096 = 128 mtiles x 32 ntiles
    const int orig  = blockIdx.x;
    const int wg    = (orig & 7) * 512 + (orig >> 3);
    const int mtile = wg & 127;
    const int nt64  = wg >> 7;          // 0..31
    const int row0  = mtile * 128;
    const int n0    = nt64 * 64;

    const unsigned char* XfT = Xf + ((size_t)(mtile * 32) << 13);
    const unsigned char* WfT = Wf + ((size_t)((nt64 >> 1) * 32) << 14);
    const int subN = (nt64 & 1) * 4096;   // 64-col sub-tile within 8 KB W tile

    f32x16 acc[4] = {};

    const int abase = lane * 16;                          // + mf*2048 + rd*1024
    const int bbase = ch * 2048 + lane * 16;              // + rd*1024

    // stage one K-tile: A 8 KB (2 loads) + K 4 KB (1) + V 4 KB (1)
    #define STAGE(T, NB)                                                                    \
        do {                                                                                \
            const unsigned char* ga = XfT + ((size_t)(T) << 13);                            \
            const unsigned char* gw = WfT + ((size_t)(T) << 14) + subN;                     \
            __builtin_amdgcn_global_load_lds((const AS1 void*)(ga + tid * 16),              \
                (AS3 void*)(Als0 + (NB) * 8192 + tid * 16), 16, 0, 0);                      \
            __builtin_amdgcn_global_load_lds((const AS1 void*)(ga + 4096 + tid * 16),       \
                (AS3 void*)(Als0 + (NB) * 8192 + 4096 + tid * 16), 16, 0, 0);               \
            __builtin_amdgcn_global_load_lds((const AS1 void*)(gw + tid * 16),              \
                (AS3 void*)(Kls0 + (NB) * 4096 + tid * 16), 16, 0, 0);                      \
            __builtin_amdgcn_global_load_lds((const AS1 void*)(gw + 8192 + tid * 16),       \
                (AS3 void*)(Vls0 + (NB) * 4096 + tid * 16), 16, 0, 0);                      \
        } while (0)

    STAGE(0, 0);

    #pragma unroll 1
    for (int it = 0; it < 16; ++it) {
        #pragma unroll
        for (int sub = 0; sub < 2; ++sub) {
            const int t = it * 2 + sub;
            const bool last = (t == 31);
            const unsigned char* As = Als0 + sub * 8192;
            const unsigned char* Bs = (kv ? Vls0 : Kls0) + sub * 4096;

            if (!last) { STAGE(t + 1, sub ^ 1); VMW(4); } else { VMW(0); }
            SCHB();
            SBAR();

            i32x8 a8[4], b8;
            #pragma unroll
            for (int mf = 0; mf < 4; ++mf) {
                i32x4 lo = *(const i32x4*)(As + abase + mf * 2048);
                i32x4 hi = *(const i32x4*)(As + abase + mf * 2048 + 1024);
                a8[mf] = __builtin_shufflevector(lo, hi, 0, 1, 2, 3, 4, 5, 6, 7);
            }
            {
                i32x4 lo = *(const i32x4*)(Bs + bbase);
                i32x4 hi = *(const i32x4*)(Bs + bbase + 1024);
                b8 = __builtin_shufflevector(lo, hi, 0, 1, 2, 3, 4, 5, 6, 7);
            }
            __builtin_amdgcn_s_setprio(1);
            #pragma unroll
            for (int mf = 0; mf < 4; ++mf)
                acc[mf] = __builtin_amdgcn_mfma_scale_f32_32x32x64_f8f6f4(
                    a8[mf], b8, acc[mf], 0, 0, 0, 0x7F7F7F7F, 0, 0x7B7B7B7B);
            __builtin_amdgcn_s_setprio(0);
            SBAR();
        }
    }

    // ---- epilogue: rotary+cos per wave; K-waves stash in LDS; V-waves reduce
    // C/D (32x32): col = lane&31, row = (reg&3) + 8*(reg>>2) + 4*lh
    const int batch = row0 >> 12;
    const int c     = n0 + ch * 32 + l31;
    const float bb  = bias[c + kv * 2048];
    const bool rot  = (c < 1024);
    const float invf = exp2f((float)(c >> 1) * NEG_L2K);
    const float sgn  = (c & 1) ? 1.0f : -1.0f;
    const int sbase  = (row0 & 4095) + 4 * lh;

    float* cosLds = (float*)SMEM;   // [2][128][32] f32 = 32 KB (reuse staging)
    __syncthreads();                // staging LDS dead; safe to repurpose

    float cs_arr[4][16];
    #pragma unroll
    for (int mf = 0; mf < 4; ++mf) {
        #pragma unroll
        for (int r = 0; r < 16; ++r) {
            const int rloc = mf * 32 + (r & 3) + 8 * (r >> 2) + 4 * lh;
            float x  = acc[mf][r] + bb;
            float px = __shfl_xor(x, 1);
            float xr = x;
            if (rot) {
                float sn, cc;
                __sincosf((float)(sbase - 4 * lh + rloc) * invf, &sn, &cc);
                xr = x * cc + px * (sgn * sn);
            }
            cs_arr[mf][r] = __cosf(xr);
            if (kv == 0)
                cosLds[ch * 4096 + rloc * 32 + l31] = cs_arr[mf][r];
        }
    }
    __syncthreads();
    if (kv == 1) {
        float colsum = 0.0f;
        #pragma unroll
        for (int mf = 0; mf < 4; ++mf) {
            #pragma unroll
            for (int r = 0; r < 16; ++r) {
                const int rloc = mf * 32 + (r & 3) + 8 * (r >> 2) + 4 * lh;
                colsum += cs_arr[mf][r] * cosLds[ch * 4096 + rloc * 32 + l31];
            }
        }
        colsum += __shfl_xor(colsum, 32);
        if (lane < 32)
            atomicAdd(&A[batch * 2048 + c], colsum);
    }
}

// ---------------- Kernel 4: out = (0.5*A + 0.5) * X --------------------
__global__ void scale_out_kernel(const float* __restrict__ X,
                                 const float* __restrict__ A,
                                 float* __restrict__ out, int n4) {
    int gid = blockIdx.x * blockDim.x + threadIdx.x;
    int stride = gridDim.x * blockDim.x;
    for (int i = gid; i < n4; i += stride) {
        int e0 = i * 4;
        int b  = e0 >> 23;        // S*D = 2^23
        int d  = e0 & 2047;
        float4 a4 = *(const float4*)(A + b * 2048 + d);
        float4 x4 = ((const float4*)X)[i];
        float4 o;
        o.x = (0.5f * a4.x + 0.5f) * x4.x;
        o.y = (0.5f * a4.y + 0.5f) * x4.y;
        o.z = (0.5f * a4.z + 0.5f) * x4.z;
        o.w = (0.5f * a4.w + 0.5f) * x4.w;
        ((float4*)out)[i] = o;
    }
}

extern "C" void kernel_launch(void* const* d_in, const int* in_sizes, int n_in,
                              void* d_out, int out_size, void* d_ws, size_t ws_size,
                              hipStream_t stream) {
    const float* X    = (const float*)d_in[0];   // [4][4096][2048]
    const float* W    = (const float*)d_in[1];   // [2048][4096]
    const float* bias = (const float*)d_in[2];   // [4096]
    float* out = (float*)d_out;

    const size_t szA  = 32768;                        // 4*2048*4 (padded)
    const size_t szWf = (size_t)4096 * 2048;          // 8.4 MB fp8
    const size_t szXf = (size_t)16384 * 2048;         // 33.5 MB fp8

    char* ws = (char*)d_ws;
    float* A = (float*)ws;                            // assume ws >= 32 KB
    unsigned char* Wf;
    unsigned char* Xf;
    if (ws_size >= szA + szWf + szXf) {
        Wf = (unsigned char*)(ws + szA);
        Xf = (unsigned char*)(ws + szA + szWf);
    } else if (ws_size >= szA + szWf) {
        Wf = (unsigned char*)(ws + szA);
        Xf = (unsigned char*)d_out;                   // scratch; rewritten by kernel 4
    } else {
        Xf = (unsigned char*)d_out;
        Wf = (unsigned char*)d_out + szXf;            // 42 MB <= 134 MB
    }

    prep_x_kernel<<<8192, 256, 0, stream>>>(X, Xf, A);
    prep_w_kernel<<<dim3(64, 32), 256, 0, stream>>>(W, Wf);
    gemm_acos_kernel<<<4096, 256, 0, stream>>>(Xf, Wf, bias, A);
    scale_out_kernel<<<2048, 256, 0, stream>>>(X, A, out, 16384 * 2048 / 4);
}

// Round 11
// 258.761 us; speedup vs baseline: 13.0956x; 1.0431x over previous
//
#include <hip/hip_runtime.h>
#include <hip/hip_bf16.h>

typedef __attribute__((ext_vector_type(4)))  int   i32x4;
typedef __attribute__((ext_vector_type(8)))  int   i32x8;
typedef __attribute__((ext_vector_type(16))) float f32x16;

#define NEG_L2K (-0.025952563241307517f)  // -log2(10000)/512

#define VMW(N) asm volatile("s_waitcnt vmcnt(" #N ")" ::: "memory")
#define SCHB() __builtin_amdgcn_sched_barrier(0)
#define SBAR() __builtin_amdgcn_s_barrier()

#define AS1 __attribute__((address_space(1)))
#define AS3 __attribute__((address_space(3)))

__device__ __forceinline__ unsigned int pk4_fp8(float a, float b, float c, float d) {
    unsigned int v = __builtin_amdgcn_cvt_pk_fp8_f32(a, b, 0, false);
    v = __builtin_amdgcn_cvt_pk_fp8_f32(c, d, v, true);
    return v;
}

// ---------------- Kernel 1: X fp32 -> fp8, fragment-major, BM=128 tiles ----
// (verified R8 — unchanged)
__global__ __launch_bounds__(256) void prep_x_kernel(const float* __restrict__ X,
                                                     unsigned char* __restrict__ Xf,
                                                     float* __restrict__ A) {
    int g = blockIdx.x * 256 + threadIdx.x;   // 0 .. 2^21-1
    if (g < 8192) A[g] = 0.0f;
    int tileid = g >> 9;       // 0..4095
    int mtile  = tileid >> 5;  // 0..127
    int kt     = tileid & 31;
    int c      = g & 511;
    int s      = c >> 6;       // 0..7 = mf*2+rd
    int lane   = c & 63;
    int row  = mtile * 128 + (s >> 1) * 32 + (lane & 31);
    int kcol = kt * 64 + (lane >> 5) * 32 + (s & 1) * 16;
    const float* src = X + (size_t)row * 2048 + kcol;
    float4 f0 = *(const float4*)(src);
    float4 f1 = *(const float4*)(src + 4);
    float4 f2 = *(const float4*)(src + 8);
    float4 f3 = *(const float4*)(src + 12);
    uint4 o;
    o.x = pk4_fp8(f0.x, f0.y, f0.z, f0.w);
    o.y = pk4_fp8(f1.x, f1.y, f1.z, f1.w);
    o.z = pk4_fp8(f2.x, f2.y, f2.z, f2.w);
    o.w = pk4_fp8(f3.x, f3.y, f3.z, f3.w);
    *(uint4*)(Xf + (size_t)g * 16) = o;
}

// ---------------- Kernel 2: W fp32 -> fp8 (x16 pre-scale) frag-major -------
// (verified R7/R8 — unchanged).  Tile (ntile,kt,KV) = 8 KB at
// ((ntile*32+kt)<<14) + (KV<<13); 4 KB halves = 64-col sub-tiles.
__global__ __launch_bounds__(256) void prep_w_kernel(const float* __restrict__ W,
                                                     unsigned char* __restrict__ Wf) {
    __shared__ unsigned char t[64][72];
    int f0 = blockIdx.x * 64;   // along 4096 (f)
    int k0 = blockIdx.y * 64;   // along 2048 (k)
    int tx = threadIdx.x & 63;
    int ty = threadIdx.x >> 6;
    for (int r = ty; r < 64; r += 4) {
        float w = W[(size_t)(k0 + r) * 4096 + f0 + tx] * 16.0f;
        t[r][tx] = (unsigned char)(__builtin_amdgcn_cvt_pk_fp8_f32(w, w, 0, false) & 0xFF);
    }
    __syncthreads();
    int c   = threadIdx.x;
    int il  = c & 31;
    int lh  = (c >> 5) & 1;
    int rd  = (c >> 6) & 1;
    int wcl = c >> 7;
    int col_l = wcl * 32 + il;          // 0..63 within block
    int kl    = lh * 32 + rd * 16;
    int fh    = f0 & 2047;
    int KV    = f0 >> 11;
    int ntile = fh >> 7;
    int wcg   = ((fh >> 5) & 2) + wcl;
    union { unsigned char b[16]; uint4 v; } ob;
    #pragma unroll
    for (int b = 0; b < 16; ++b) ob.b[b] = t[kl + b][col_l];
    size_t base = ((((size_t)ntile * 32 + blockIdx.y) * 2 + KV) << 13)
                + (size_t)(((wcg * 2 + rd) * 64 + lh * 32 + il) << 4);
    *(uint4*)(Wf + base) = ob.v;
}

// ---------------- Kernel 3: fused fp8 GEMM + rotary + cos*cos + reduce ----
// Big-tile / 1-wave-per-SIMD: BM=128, BN=256(K)+256(V), 4 waves; wave w owns
// 128 rows x 64 cols of BOTH K and V (acc = 256 regs).  LDS reads/MFMA = 1.0
// (vs R8's 1.5) -> LDS no longer co-bottleneck.  Deep prefetch: issue tile
// t+1's 10 loads, then VMW(10); 2 barriers/K-step.
__global__ __launch_bounds__(256, 1) void gemm_acos_kernel(
    const unsigned char* __restrict__ Xf,
    const unsigned char* __restrict__ Wf,
    const float* __restrict__ bias,
    float* __restrict__ A)
{
    __shared__ __align__(16) unsigned char Als[2][8192];    // 16 KB
    __shared__ __align__(16) unsigned char Kls[2][16384];   // 32 KB
    __shared__ __align__(16) unsigned char Vls[2][16384];   // 32 KB

    const int tid  = threadIdx.x;
    const int lane = tid & 63;
    const int w    = tid >> 6;    // 0..3 : 64-col slice (of 256)
    const int l31  = lane & 31;
    const int lh   = lane >> 5;

    // T1: bijective XCD swizzle, grid 1024 = 128 mtiles x 8 npairs
    const int orig  = blockIdx.x;
    const int wg    = (orig & 7) * 128 + (orig >> 3);
    const int mtile = wg & 127;
    const int npair = wg >> 7;          // 0..7 (256-col group)
    const int row0  = mtile * 128;
    const int n0    = npair * 256;

    const unsigned char* XfT = Xf + ((size_t)(mtile * 32) << 13);
    const unsigned char* W0  = Wf + ((size_t)(npair * 2) * 32 << 14);
    const unsigned char* W1  = W0 + ((size_t)32 << 14);

    f32x16 accK[4][2] = {};
    f32x16 accV[4][2] = {};

    const int abase = lane * 16;                              // + mf*2048 (+1024)
    const int bbase = (w >> 1) * 8192 + (w & 1) * 4096 + lane * 16;  // + n*2048 (+1024)

    // stage tile T: A 8 KB (2) + K 16 KB (4) + V 16 KB (4) = 10 loads/thread
    #define STAGE(T, NB)                                                                    \
        do {                                                                                \
            const unsigned char* ga  = XfT + ((size_t)(T) << 13);                           \
            const unsigned char* gk0 = W0 + ((size_t)(T) << 14);                            \
            const unsigned char* gk1 = W1 + ((size_t)(T) << 14);                            \
            __builtin_amdgcn_global_load_lds((const AS1 void*)(ga + tid * 16),              \
                (AS3 void*)(Als[NB] + tid * 16), 16, 0, 0);                                 \
            __builtin_amdgcn_global_load_lds((const AS1 void*)(ga + 4096 + tid * 16),       \
                (AS3 void*)(Als[NB] + 4096 + tid * 16), 16, 0, 0);                          \
            __builtin_amdgcn_global_load_lds((const AS1 void*)(gk0 + tid * 16),             \
                (AS3 void*)(Kls[NB] + tid * 16), 16, 0, 0);                                 \
            __builtin_amdgcn_global_load_lds((const AS1 void*)(gk0 + 4096 + tid * 16),      \
                (AS3 void*)(Kls[NB] + 4096 + tid * 16), 16, 0, 0);                          \
            __builtin_amdgcn_global_load_lds((const AS1 void*)(gk1 + tid * 16),             \
                (AS3 void*)(Kls[NB] + 8192 + tid * 16), 16, 0, 0);                          \
            __builtin_amdgcn_global_load_lds((const AS1 void*)(gk1 + 4096 + tid * 16),      \
                (AS3 void*)(Kls[NB] + 12288 + tid * 16), 16, 0, 0);                         \
            __builtin_amdgcn_global_load_lds((const AS1 void*)(gk0 + 8192 + tid * 16),      \
                (AS3 void*)(Vls[NB] + tid * 16), 16, 0, 0);                                 \
            __builtin_amdgcn_global_load_lds((const AS1 void*)(gk0 + 12288 + tid * 16),     \
                (AS3 void*)(Vls[NB] + 4096 + tid * 16), 16, 0, 0);                          \
            __builtin_amdgcn_global_load_lds((const AS1 void*)(gk1 + 8192 + tid * 16),      \
                (AS3 void*)(Vls[NB] + 8192 + tid * 16), 16, 0, 0);                          \
            __builtin_amdgcn_global_load_lds((const AS1 void*)(gk1 + 12288 + tid * 16),     \
                (AS3 void*)(Vls[NB] + 12288 + tid * 16), 16, 0, 0);                         \
        } while (0)

    STAGE(0, 0);

    #pragma unroll 1
    for (int it = 0; it < 16; ++it) {
        #pragma unroll
        for (int sub = 0; sub < 2; ++sub) {
            const int t = it * 2 + sub;
            const bool last = (t == 31);
            const unsigned char* As = Als[sub];
            const unsigned char* Ks = Kls[sub];
            const unsigned char* Vs = Vls[sub];

            if (!last) { STAGE(t + 1, sub ^ 1); VMW(10); } else { VMW(0); }
            SCHB();
            SBAR();

            i32x8 a8[4], bk8[2], bv8[2];
            #pragma unroll
            for (int mf = 0; mf < 4; ++mf) {
                i32x4 lo = *(const i32x4*)(As + abase + mf * 2048);
                i32x4 hi = *(const i32x4*)(As + abase + mf * 2048 + 1024);
                a8[mf] = __builtin_shufflevector(lo, hi, 0, 1, 2, 3, 4, 5, 6, 7);
            }
            #pragma unroll
            for (int n = 0; n < 2; ++n) {
                i32x4 lo = *(const i32x4*)(Ks + bbase + n * 2048);
                i32x4 hi = *(const i32x4*)(Ks + bbase + n * 2048 + 1024);
                bk8[n] = __builtin_shufflevector(lo, hi, 0, 1, 2, 3, 4, 5, 6, 7);
            }
            __builtin_amdgcn_s_setprio(1);
            #pragma unroll
            for (int mf = 0; mf < 4; ++mf)
                #pragma unroll
                for (int n = 0; n < 2; ++n)
                    accK[mf][n] = __builtin_amdgcn_mfma_scale_f32_32x32x64_f8f6f4(
                        a8[mf], bk8[n], accK[mf][n], 0, 0, 0, 0x7F7F7F7F, 0, 0x7B7B7B7B);
            __builtin_amdgcn_s_setprio(0);

            #pragma unroll
            for (int n = 0; n < 2; ++n) {
                i32x4 lo = *(const i32x4*)(Vs + bbase + n * 2048);
                i32x4 hi = *(const i32x4*)(Vs + bbase + n * 2048 + 1024);
                bv8[n] = __builtin_shufflevector(lo, hi, 0, 1, 2, 3, 4, 5, 6, 7);
            }
            __builtin_amdgcn_s_setprio(1);
            #pragma unroll
            for (int mf = 0; mf < 4; ++mf)
                #pragma unroll
                for (int n = 0; n < 2; ++n)
                    accV[mf][n] = __builtin_amdgcn_mfma_scale_f32_32x32x64_f8f6f4(
                        a8[mf], bv8[n], accV[mf][n], 0, 0, 0, 0x7F7F7F7F, 0, 0x7B7B7B7B);
            __builtin_amdgcn_s_setprio(0);
            SBAR();                 // all reads of buf[sub] done before t+2 stage
        }
    }

    // ---- epilogue: bias, rotary, cos*cos, reduce over rows, atomicAdd
    // C/D (32x32): col = lane&31, row = (reg&3) + 8*(reg>>2) + 4*lh
    const int batch = row0 >> 12;
    const int sbase = (row0 & 4095) + 4 * lh;

    #pragma unroll
    for (int n = 0; n < 2; ++n) {
        const int c     = n0 + w * 64 + n * 32 + l31;
        const float bK  = bias[c];
        const float bV  = bias[c + 2048];
        const bool rot  = (c < 1024);
        const float invf = exp2f((float)(c >> 1) * NEG_L2K);
        const float sgn  = (c & 1) ? 1.0f : -1.0f;
        float colsum = 0.0f;
        #pragma unroll
        for (int mf = 0; mf < 4; ++mf) {
            #pragma unroll
            for (int r = 0; r < 16; ++r) {
                const int srow = sbase + mf * 32 + (r & 3) + 8 * (r >> 2);
                float kv = accK[mf][n][r] + bK;
                float vv = accV[mf][n][r] + bV;
                float pk = __shfl_xor(kv, 1);
                float pv = __shfl_xor(vv, 1);
                float kr = kv, vr = vv;
                if (rot) {
                    float sn, cs;
                    __sincosf((float)srow * invf, &sn, &cs);
                    float tt = sgn * sn;
                    kr = kv * cs + pk * tt;
                    vr = vv * cs + pv * tt;
                }
                colsum += __cosf(kr) * __cosf(vr);
            }
        }
        colsum += __shfl_xor(colsum, 32);
        if (lane < 32)
            atomicAdd(&A[batch * 2048 + c], colsum);
    }
}

// ---------------- Kernel 4: out = (0.5*A + 0.5) * X --------------------
__global__ void scale_out_kernel(const float* __restrict__ X,
                                 const float* __restrict__ A,
                                 float* __restrict__ out, int n4) {
    int gid = blockIdx.x * blockDim.x + threadIdx.x;
    int stride = gridDim.x * blockDim.x;
    for (int i = gid; i < n4; i += stride) {
        int e0 = i * 4;
        int b  = e0 >> 23;        // S*D = 2^23
        int d  = e0 & 2047;
        float4 a4 = *(const float4*)(A + b * 2048 + d);
        float4 x4 = ((const float4*)X)[i];
        float4 o;
        o.x = (0.5f * a4.x + 0.5f) * x4.x;
        o.y = (0.5f * a4.y + 0.5f) * x4.y;
        o.z = (0.5f * a4.z + 0.5f) * x4.z;
        o.w = (0.5f * a4.w + 0.5f) * x4.w;
        ((float4*)out)[i] = o;
    }
}

extern "C" void kernel_launch(void* const* d_in, const int* in_sizes, int n_in,
                              void* d_out, int out_size, void* d_ws, size_t ws_size,
                              hipStream_t stream) {
    const float* X    = (const float*)d_in[0];   // [4][4096][2048]
    const float* W    = (const float*)d_in[1];   // [2048][4096]
    const float* bias = (const float*)d_in[2];   // [4096]
    float* out = (float*)d_out;

    const size_t szA  = 32768;                        // 4*2048*4 (padded)
    const size_t szWf = (size_t)4096 * 2048;          // 8.4 MB fp8
    const size_t szXf = (size_t)16384 * 2048;         // 33.5 MB fp8

    char* ws = (char*)d_ws;
    float* A = (float*)ws;                            // assume ws >= 32 KB
    unsigned char* Wf;
    unsigned char* Xf;
    if (ws_size >= szA + szWf + szXf) {
        Wf = (unsigned char*)(ws + szA);
        Xf = (unsigned char*)(ws + szA + szWf);
    } else if (ws_size >= szA + szWf) {
        Wf = (unsigned char*)(ws + szA);
        Xf = (unsigned char*)d_out;                   // scratch; rewritten by kernel 4
    } else {
        Xf = (unsigned char*)d_out;
        Wf = (unsigned char*)d_out + szXf;            // 42 MB <= 134 MB
    }

    prep_x_kernel<<<8192, 256, 0, stream>>>(X, Xf, A);
    prep_w_kernel<<<dim3(64, 32), 256, 0, stream>>>(W, Wf);
    gemm_acos_kernel<<<1024, 256, 0, stream>>>(Xf, Wf, bias, A);
    scale_out_kernel<<<2048, 256, 0, stream>>>(X, A, out, 16384 * 2048 / 4);
}

// Round 12
// 242.081 us; speedup vs baseline: 13.9979x; 1.0689x over previous
//
#include <hip/hip_runtime.h>
#include <hip/hip_bf16.h>

typedef __attribute__((ext_vector_type(4)))  int   i32x4;
typedef __attribute__((ext_vector_type(8)))  int   i32x8;
typedef __attribute__((ext_vector_type(16))) float f32x16;

#define NEG_L2K (-0.025952563241307517f)  // -log2(10000)/512

#define VMW(N) asm volatile("s_waitcnt vmcnt(" #N ")" ::: "memory")
#define SCHB() __builtin_amdgcn_sched_barrier(0)
#define SBAR() __builtin_amdgcn_s_barrier()

#define AS1 __attribute__((address_space(1)))
#define AS3 __attribute__((address_space(3)))

__device__ __forceinline__ unsigned int pk4_fp8(float a, float b, float c, float d) {
    unsigned int v = __builtin_amdgcn_cvt_pk_fp8_f32(a, b, 0, false);
    v = __builtin_amdgcn_cvt_pk_fp8_f32(c, d, v, true);
    return v;
}

// ---------------- Kernel 1: X fp32 -> fp8, fragment-major, BM=128 tiles ----
// (verified R8 — unchanged)
__global__ __launch_bounds__(256) void prep_x_kernel(const float* __restrict__ X,
                                                     unsigned char* __restrict__ Xf,
                                                     float* __restrict__ A) {
    int g = blockIdx.x * 256 + threadIdx.x;   // 0 .. 2^21-1
    if (g < 8192) A[g] = 0.0f;
    int tileid = g >> 9;       // 0..4095
    int mtile  = tileid >> 5;  // 0..127
    int kt     = tileid & 31;
    int c      = g & 511;
    int s      = c >> 6;       // 0..7 = mf*2+rd
    int lane   = c & 63;
    int row  = mtile * 128 + (s >> 1) * 32 + (lane & 31);
    int kcol = kt * 64 + (lane >> 5) * 32 + (s & 1) * 16;
    const float* src = X + (size_t)row * 2048 + kcol;
    float4 f0 = *(const float4*)(src);
    float4 f1 = *(const float4*)(src + 4);
    float4 f2 = *(const float4*)(src + 8);
    float4 f3 = *(const float4*)(src + 12);
    uint4 o;
    o.x = pk4_fp8(f0.x, f0.y, f0.z, f0.w);
    o.y = pk4_fp8(f1.x, f1.y, f1.z, f1.w);
    o.z = pk4_fp8(f2.x, f2.y, f2.z, f2.w);
    o.w = pk4_fp8(f3.x, f3.y, f3.z, f3.w);
    *(uint4*)(Xf + (size_t)g * 16) = o;
}

// ---------------- Kernel 2: W fp32 -> fp8 (x16 pre-scale) frag-major -------
// (verified R7/R8 — unchanged)
__global__ __launch_bounds__(256) void prep_w_kernel(const float* __restrict__ W,
                                                     unsigned char* __restrict__ Wf) {
    __shared__ unsigned char t[64][72];
    int f0 = blockIdx.x * 64;   // along 4096 (f)
    int k0 = blockIdx.y * 64;   // along 2048 (k)
    int tx = threadIdx.x & 63;
    int ty = threadIdx.x >> 6;
    for (int r = ty; r < 64; r += 4) {
        float w = W[(size_t)(k0 + r) * 4096 + f0 + tx] * 16.0f;
        t[r][tx] = (unsigned char)(__builtin_amdgcn_cvt_pk_fp8_f32(w, w, 0, false) & 0xFF);
    }
    __syncthreads();
    int c   = threadIdx.x;
    int il  = c & 31;
    int lh  = (c >> 5) & 1;
    int rd  = (c >> 6) & 1;
    int wcl = c >> 7;
    int col_l = wcl * 32 + il;          // 0..63 within block
    int kl    = lh * 32 + rd * 16;
    int fh    = f0 & 2047;
    int KV    = f0 >> 11;
    int ntile = fh >> 7;
    int wcg   = ((fh >> 5) & 2) + wcl;
    union { unsigned char b[16]; uint4 v; } ob;
    #pragma unroll
    for (int b = 0; b < 16; ++b) ob.b[b] = t[kl + b][col_l];
    size_t base = ((((size_t)ntile * 32 + blockIdx.y) * 2 + KV) << 13)
                + (size_t)(((wcg * 2 + rd) * 64 + lh * 32 + il) << 4);
    *(uint4*)(Wf + base) = ob.v;
}

// ---------------- Kernel 3: fused fp8 GEMM + rotary + cos*cos + reduce ----
// R8 shape (4 waves, BM=128, BN=128 K+V, acc 128, 2 blocks/CU) with a
// triple-buffered single-barrier pipeline: prefetch distance 2 tiles, so
// VMW(6) waits on loads issued ~2600 cyc earlier (never blocks), and the
// stage-after-barrier ordering makes the 2nd barrier provably unnecessary.
__global__ __launch_bounds__(256, 2) void gemm_acos_kernel(
    const unsigned char* __restrict__ Xf,
    const unsigned char* __restrict__ Wf,
    const float* __restrict__ bias,
    float* __restrict__ A)
{
    __shared__ __align__(16) unsigned char Als0[3 * 8192];
    __shared__ __align__(16) unsigned char Kls0[3 * 8192];
    __shared__ __align__(16) unsigned char Vls0[3 * 8192];

    const int tid  = threadIdx.x;
    const int lane = tid & 63;
    const int wc   = tid >> 6;    // 0..3  col quarter (32 cols)
    const int l31  = lane & 31;
    const int lh   = lane >> 5;

    // T1: bijective XCD swizzle, grid 2048 = 128 mtiles x 16 ntiles
    const int orig  = blockIdx.x;
    const int wg    = (orig & 7) * 256 + (orig >> 3);
    const int mtile = wg & 127;
    const int ntile = wg >> 7;
    const int row0  = mtile * 128;
    const int n0    = ntile * 128;

    const unsigned char* XfT = Xf + ((size_t)(mtile * 32) << 13);
    const unsigned char* WfT = Wf + ((size_t)(ntile * 32) << 14);

    f32x16 accK[4] = {};
    f32x16 accV[4] = {};

    const int abase = lane * 16;                 // + mf*2048 + rd*1024
    const int bbase = (wc * 128 + lane) * 16;    // + rd*1024

    // stage one K-tile (A 8 KB, K 8 KB, V 8 KB) -> 6 loads/thread
    #define STAGE(T, NB)                                                                    \
        do {                                                                                \
            const unsigned char* ga = XfT + ((size_t)(T) << 13);                            \
            const unsigned char* gw = WfT + ((size_t)(T) << 14);                            \
            __builtin_amdgcn_global_load_lds((const AS1 void*)(ga + tid * 16),              \
                (AS3 void*)(Als0 + (NB) * 8192 + tid * 16), 16, 0, 0);                      \
            __builtin_amdgcn_global_load_lds((const AS1 void*)(ga + 4096 + tid * 16),       \
                (AS3 void*)(Als0 + (NB) * 8192 + 4096 + tid * 16), 16, 0, 0);               \
            __builtin_amdgcn_global_load_lds((const AS1 void*)(gw + tid * 16),              \
                (AS3 void*)(Kls0 + (NB) * 8192 + tid * 16), 16, 0, 0);                      \
            __builtin_amdgcn_global_load_lds((const AS1 void*)(gw + 4096 + tid * 16),       \
                (AS3 void*)(Kls0 + (NB) * 8192 + 4096 + tid * 16), 16, 0, 0);               \
            __builtin_amdgcn_global_load_lds((const AS1 void*)(gw + 8192 + tid * 16),       \
                (AS3 void*)(Vls0 + (NB) * 8192 + tid * 16), 16, 0, 0);                      \
            __builtin_amdgcn_global_load_lds((const AS1 void*)(gw + 12288 + tid * 16),      \
                (AS3 void*)(Vls0 + (NB) * 8192 + 4096 + tid * 16), 16, 0, 0);               \
        } while (0)

    // prologue: 2 tiles in flight (12 outstanding loads)
    STAGE(0, 0);
    STAGE(1, 1);

    #pragma unroll 1
    for (int t = 0; t < 32; ++t) {
        const int cur = t % 3;
        const unsigned char* As = Als0 + cur * 8192;
        const unsigned char* Ks = Kls0 + cur * 8192;
        const unsigned char* Vs = Vls0 + cur * 8192;

        // drain tile t's 6 loads (issued 2 steps ago); keep t+1's in flight
        if (t < 31) { VMW(6); } else { VMW(0); }
        SCHB();
        SBAR();   // single barrier: tile t visible; also fences buffer reuse

        // issue tile t+2 into buf (t+2)%3 — its previous readers (step t-1)
        // finished before this barrier (their MFMAs forced lgkmcnt drain)
        if (t < 30) STAGE(t + 2, (t + 2) % 3);

        i32x8 a8[4], bk8, bv8;
        #pragma unroll
        for (int mf = 0; mf < 4; ++mf) {
            i32x4 lo = *(const i32x4*)(As + abase + mf * 2048);
            i32x4 hi = *(const i32x4*)(As + abase + mf * 2048 + 1024);
            a8[mf] = __builtin_shufflevector(lo, hi, 0, 1, 2, 3, 4, 5, 6, 7);
        }
        {
            i32x4 lo = *(const i32x4*)(Ks + bbase);
            i32x4 hi = *(const i32x4*)(Ks + bbase + 1024);
            bk8 = __builtin_shufflevector(lo, hi, 0, 1, 2, 3, 4, 5, 6, 7);
        }
        __builtin_amdgcn_s_setprio(1);
        #pragma unroll
        for (int mf = 0; mf < 4; ++mf)
            accK[mf] = __builtin_amdgcn_mfma_scale_f32_32x32x64_f8f6f4(
                a8[mf], bk8, accK[mf], 0, 0, 0, 0x7F7F7F7F, 0, 0x7B7B7B7B);
        __builtin_amdgcn_s_setprio(0);

        {
            i32x4 lo = *(const i32x4*)(Vs + bbase);
            i32x4 hi = *(const i32x4*)(Vs + bbase + 1024);
            bv8 = __builtin_shufflevector(lo, hi, 0, 1, 2, 3, 4, 5, 6, 7);
        }
        __builtin_amdgcn_s_setprio(1);
        #pragma unroll
        for (int mf = 0; mf < 4; ++mf)
            accV[mf] = __builtin_amdgcn_mfma_scale_f32_32x32x64_f8f6f4(
                a8[mf], bv8, accV[mf], 0, 0, 0, 0x7F7F7F7F, 0, 0x7B7B7B7B);
        __builtin_amdgcn_s_setprio(0);
    }

    // ---- epilogue: bias, rotary, cos*cos, reduce over rows, atomicAdd
    // C/D (32x32): col = lane&31, row = (reg&3) + 8*(reg>>2) + 4*lh
    const int batch = row0 >> 12;
    const int c     = n0 + wc * 32 + l31;
    const float bK  = bias[c];
    const float bV  = bias[c + 2048];
    const bool rot  = (c < 1024);
    const float invf = exp2f((float)(c >> 1) * NEG_L2K);
    const float sgn  = (c & 1) ? 1.0f : -1.0f;
    const int sbase  = (row0 & 4095) + 4 * lh;

    float colsum = 0.0f;
    #pragma unroll
    for (int mf = 0; mf < 4; ++mf) {
        #pragma unroll
        for (int r = 0; r < 16; ++r) {
            const int srow = sbase + mf * 32 + (r & 3) + 8 * (r >> 2);
            float kv = accK[mf][r] + bK;
            float vv = accV[mf][r] + bV;
            float pk = __shfl_xor(kv, 1);
            float pv = __shfl_xor(vv, 1);
            float kr = kv, vr = vv;
            if (rot) {
                float sn, cs;
                __sincosf((float)srow * invf, &sn, &cs);
                float tt = sgn * sn;
                kr = kv * cs + pk * tt;
                vr = vv * cs + pv * tt;
            }
            colsum += __cosf(kr) * __cosf(vr);
        }
    }
    colsum += __shfl_xor(colsum, 32);
    if (lane < 32)
        atomicAdd(&A[batch * 2048 + c], colsum);
}

// ---------------- Kernel 4: out = (0.5*A + 0.5) * X --------------------
__global__ void scale_out_kernel(const float* __restrict__ X,
                                 const float* __restrict__ A,
                                 float* __restrict__ out, int n4) {
    int gid = blockIdx.x * blockDim.x + threadIdx.x;
    int stride = gridDim.x * blockDim.x;
    for (int i = gid; i < n4; i += stride) {
        int e0 = i * 4;
        int b  = e0 >> 23;        // S*D = 2^23
        int d  = e0 & 2047;
        float4 a4 = *(const float4*)(A + b * 2048 + d);
        float4 x4 = ((const float4*)X)[i];
        float4 o;
        o.x = (0.5f * a4.x + 0.5f) * x4.x;
        o.y = (0.5f * a4.y + 0.5f) * x4.y;
        o.z = (0.5f * a4.z + 0.5f) * x4.z;
        o.w = (0.5f * a4.w + 0.5f) * x4.w;
        ((float4*)out)[i] = o;
    }
}

extern "C" void kernel_launch(void* const* d_in, const int* in_sizes, int n_in,
                              void* d_out, int out_size, void* d_ws, size_t ws_size,
                              hipStream_t stream) {
    const float* X    = (const float*)d_in[0];   // [4][4096][2048]
    const float* W    = (const float*)d_in[1];   // [2048][4096]
    const float* bias = (const float*)d_in[2];   // [4096]
    float* out = (float*)d_out;

    const size_t szA  = 32768;                        // 4*2048*4 (padded)
    const size_t szWf = (size_t)4096 * 2048;          // 8.4 MB fp8
    const size_t szXf = (size_t)16384 * 2048;         // 33.5 MB fp8

    char* ws = (char*)d_ws;
    float* A = (float*)ws;                            // assume ws >= 32 KB
    unsigned char* Wf;
    unsigned char* Xf;
    if (ws_size >= szA + szWf + szXf) {
        Wf = (unsigned char*)(ws + szA);
        Xf = (unsigned char*)(ws + szA + szWf);
    } else if (ws_size >= szA + szWf) {
        Wf = (unsigned char*)(ws + szA);
        Xf = (unsigned char*)d_out;                   // scratch; rewritten by kernel 4
    } else {
        Xf = (unsigned char*)d_out;
        Wf = (unsigned char*)d_out + szXf;            // 42 MB <= 134 MB
    }

    prep_x_kernel<<<8192, 256, 0, stream>>>(X, Xf, A);
    prep_w_kernel<<<dim3(64, 32), 256, 0, stream>>>(W, Wf);
    gemm_acos_kernel<<<2048, 256, 0, stream>>>(Xf, Wf, bias, A);
    scale_out_kernel<<<2048, 256, 0, stream>>>(X, A, out, 16384 * 2048 / 4);
}

// Round 13
// 237.951 us; speedup vs baseline: 14.2409x; 1.0174x over previous
//
#include <hip/hip_runtime.h>
#include <hip/hip_bf16.h>

typedef __attribute__((ext_vector_type(4)))  int   i32x4;
typedef __attribute__((ext_vector_type(8)))  int   i32x8;
typedef __attribute__((ext_vector_type(16))) float f32x16;

#define NEG_L2K (-0.025952563241307517f)  // -log2(10000)/512

#define VMW(N) asm volatile("s_waitcnt vmcnt(" #N ")" ::: "memory")
#define SCHB() __builtin_amdgcn_sched_barrier(0)
#define SBAR() __builtin_amdgcn_s_barrier()

#define AS1 __attribute__((address_space(1)))
#define AS3 __attribute__((address_space(3)))

__device__ __forceinline__ unsigned int pk4_fp8(float a, float b, float c, float d) {
    unsigned int v = __builtin_amdgcn_cvt_pk_fp8_f32(a, b, 0, false);
    v = __builtin_amdgcn_cvt_pk_fp8_f32(c, d, v, true);
    return v;
}

// ---------------- Kernel 1: X fp32 -> fp8, fragment-major, BM=128 tiles ----
// (verified R8 — unchanged)
__global__ __launch_bounds__(256) void prep_x_kernel(const float* __restrict__ X,
                                                     unsigned char* __restrict__ Xf,
                                                     float* __restrict__ A) {
    int g = blockIdx.x * 256 + threadIdx.x;   // 0 .. 2^21-1
    if (g < 8192) A[g] = 0.0f;
    int tileid = g >> 9;       // 0..4095
    int mtile  = tileid >> 5;  // 0..127
    int kt     = tileid & 31;
    int c      = g & 511;
    int s      = c >> 6;       // 0..7 = mf*2+rd
    int lane   = c & 63;
    int row  = mtile * 128 + (s >> 1) * 32 + (lane & 31);
    int kcol = kt * 64 + (lane >> 5) * 32 + (s & 1) * 16;
    const float* src = X + (size_t)row * 2048 + kcol;
    float4 f0 = *(const float4*)(src);
    float4 f1 = *(const float4*)(src + 4);
    float4 f2 = *(const float4*)(src + 8);
    float4 f3 = *(const float4*)(src + 12);
    uint4 o;
    o.x = pk4_fp8(f0.x, f0.y, f0.z, f0.w);
    o.y = pk4_fp8(f1.x, f1.y, f1.z, f1.w);
    o.z = pk4_fp8(f2.x, f2.y, f2.z, f2.w);
    o.w = pk4_fp8(f3.x, f3.y, f3.z, f3.w);
    *(uint4*)(Xf + (size_t)g * 16) = o;
}

// ---------------- Kernel 2: W fp32 -> fp8 (x16 pre-scale) frag-major -------
// (verified R7/R8 — unchanged)
__global__ __launch_bounds__(256) void prep_w_kernel(const float* __restrict__ W,
                                                     unsigned char* __restrict__ Wf) {
    __shared__ unsigned char t[64][72];
    int f0 = blockIdx.x * 64;   // along 4096 (f)
    int k0 = blockIdx.y * 64;   // along 2048 (k)
    int tx = threadIdx.x & 63;
    int ty = threadIdx.x >> 6;
    for (int r = ty; r < 64; r += 4) {
        float w = W[(size_t)(k0 + r) * 4096 + f0 + tx] * 16.0f;
        t[r][tx] = (unsigned char)(__builtin_amdgcn_cvt_pk_fp8_f32(w, w, 0, false) & 0xFF);
    }
    __syncthreads();
    int c   = threadIdx.x;
    int il  = c & 31;
    int lh  = (c >> 5) & 1;
    int rd  = (c >> 6) & 1;
    int wcl = c >> 7;
    int col_l = wcl * 32 + il;          // 0..63 within block
    int kl    = lh * 32 + rd * 16;
    int fh    = f0 & 2047;
    int KV    = f0 >> 11;
    int ntile = fh >> 7;
    int wcg   = ((fh >> 5) & 2) + wcl;
    union { unsigned char b[16]; uint4 v; } ob;
    #pragma unroll
    for (int b = 0; b < 16; ++b) ob.b[b] = t[kl + b][col_l];
    size_t base = ((((size_t)ntile * 32 + blockIdx.y) * 2 + KV) << 13)
                + (size_t)(((wcg * 2 + rd) * 64 + lh * 32 + il) << 4);
    *(uint4*)(Wf + base) = ob.v;
}

// ---------------- Kernel 3: fused fp8 GEMM + rotary + cos*cos + reduce ----
// R8 schedule (stage-before-wait, counted vmcnt, 2 barriers, 2 blocks/CU)
// deepened to prefetch distance 2 via triple-buffered LDS (72 KB/block).
// Ledger: prologue stages t0,t1 (12 outstanding); step t issues stage(t+2)
// (18), VMW(12) drains exactly stage(t); t=30: VMW(6); t=31: VMW(0).
__global__ __launch_bounds__(256, 2) void gemm_acos_kernel(
    const unsigned char* __restrict__ Xf,
    const unsigned char* __restrict__ Wf,
    const float* __restrict__ bias,
    float* __restrict__ A)
{
    __shared__ __align__(16) unsigned char Als0[3 * 8192];
    __shared__ __align__(16) unsigned char Kls0[3 * 8192];
    __shared__ __align__(16) unsigned char Vls0[3 * 8192];

    const int tid  = threadIdx.x;
    const int lane = tid & 63;
    const int wc   = tid >> 6;    // 0..3  col quarter (32 cols)
    const int l31  = lane & 31;
    const int lh   = lane >> 5;

    // T1: bijective XCD swizzle, grid 2048 = 128 mtiles x 16 ntiles
    const int orig  = blockIdx.x;
    const int wg    = (orig & 7) * 256 + (orig >> 3);
    const int mtile = wg & 127;
    const int ntile = wg >> 7;
    const int row0  = mtile * 128;
    const int n0    = ntile * 128;

    const unsigned char* XfT = Xf + ((size_t)(mtile * 32) << 13);
    const unsigned char* WfT = Wf + ((size_t)(ntile * 32) << 14);

    f32x16 accK[4] = {};
    f32x16 accV[4] = {};

    const int abase = lane * 16;                 // + mf*2048 + rd*1024
    const int bbase = (wc * 128 + lane) * 16;    // + rd*1024

    // stage one K-tile (A 8 KB, K 8 KB, V 8 KB) -> 6 loads/thread
    #define STAGE(T, NB)                                                                    \
        do {                                                                                \
            const unsigned char* ga = XfT + ((size_t)(T) << 13);                            \
            const unsigned char* gw = WfT + ((size_t)(T) << 14);                            \
            __builtin_amdgcn_global_load_lds((const AS1 void*)(ga + tid * 16),              \
                (AS3 void*)(Als0 + (NB) * 8192 + tid * 16), 16, 0, 0);                      \
            __builtin_amdgcn_global_load_lds((const AS1 void*)(ga + 4096 + tid * 16),       \
                (AS3 void*)(Als0 + (NB) * 8192 + 4096 + tid * 16), 16, 0, 0);               \
            __builtin_amdgcn_global_load_lds((const AS1 void*)(gw + tid * 16),              \
                (AS3 void*)(Kls0 + (NB) * 8192 + tid * 16), 16, 0, 0);                      \
            __builtin_amdgcn_global_load_lds((const AS1 void*)(gw + 4096 + tid * 16),       \
                (AS3 void*)(Kls0 + (NB) * 8192 + 4096 + tid * 16), 16, 0, 0);               \
            __builtin_amdgcn_global_load_lds((const AS1 void*)(gw + 8192 + tid * 16),       \
                (AS3 void*)(Vls0 + (NB) * 8192 + tid * 16), 16, 0, 0);                      \
            __builtin_amdgcn_global_load_lds((const AS1 void*)(gw + 12288 + tid * 16),      \
                (AS3 void*)(Vls0 + (NB) * 8192 + 4096 + tid * 16), 16, 0, 0);               \
        } while (0)

    // prologue: 2 tiles in flight (12 outstanding loads)
    STAGE(0, 0);
    STAGE(1, 1);

    #pragma unroll 1
    for (int t = 0; t < 32; ++t) {
        const int cur = t % 3;
        const unsigned char* As = Als0 + cur * 8192;
        const unsigned char* Ks = Kls0 + cur * 8192;
        const unsigned char* Vs = Vls0 + cur * 8192;

        // issue stage(t+2) first (early issue, R8 property); then drain
        // exactly stage(t): counted wait on loads issued ~2 K-steps ago.
        if (t < 30) {
            STAGE(t + 2, (t + 2) % 3);
            VMW(12);
        } else if (t == 30) {
            VMW(6);
        } else {
            VMW(0);
        }
        SCHB();
        SBAR();   // tile t visible to all waves

        i32x8 a8[4], bk8, bv8;
        #pragma unroll
        for (int mf = 0; mf < 4; ++mf) {
            i32x4 lo = *(const i32x4*)(As + abase + mf * 2048);
            i32x4 hi = *(const i32x4*)(As + abase + mf * 2048 + 1024);
            a8[mf] = __builtin_shufflevector(lo, hi, 0, 1, 2, 3, 4, 5, 6, 7);
        }
        {
            i32x4 lo = *(const i32x4*)(Ks + bbase);
            i32x4 hi = *(const i32x4*)(Ks + bbase + 1024);
            bk8 = __builtin_shufflevector(lo, hi, 0, 1, 2, 3, 4, 5, 6, 7);
        }
        __builtin_amdgcn_s_setprio(1);
        #pragma unroll
        for (int mf = 0; mf < 4; ++mf)
            accK[mf] = __builtin_amdgcn_mfma_scale_f32_32x32x64_f8f6f4(
                a8[mf], bk8, accK[mf], 0, 0, 0, 0x7F7F7F7F, 0, 0x7B7B7B7B);
        __builtin_amdgcn_s_setprio(0);

        {
            i32x4 lo = *(const i32x4*)(Vs + bbase);
            i32x4 hi = *(const i32x4*)(Vs + bbase + 1024);
            bv8 = __builtin_shufflevector(lo, hi, 0, 1, 2, 3, 4, 5, 6, 7);
        }
        __builtin_amdgcn_s_setprio(1);
        #pragma unroll
        for (int mf = 0; mf < 4; ++mf)
            accV[mf] = __builtin_amdgcn_mfma_scale_f32_32x32x64_f8f6f4(
                a8[mf], bv8, accV[mf], 0, 0, 0, 0x7F7F7F7F, 0, 0x7B7B7B7B);
        __builtin_amdgcn_s_setprio(0);
        SBAR();   // all reads of buf[cur] done before its re-stage at t+1
    }

    // ---- epilogue: bias, rotary, cos*cos, reduce over rows, atomicAdd
    // C/D (32x32): col = lane&31, row = (reg&3) + 8*(reg>>2) + 4*lh
    const int batch = row0 >> 12;
    const int c     = n0 + wc * 32 + l31;
    const float bK  = bias[c];
    const float bV  = bias[c + 2048];
    const bool rot  = (c < 1024);
    const float invf = exp2f((float)(c >> 1) * NEG_L2K);
    const float sgn  = (c & 1) ? 1.0f : -1.0f;
    const int sbase  = (row0 & 4095) + 4 * lh;

    float colsum = 0.0f;
    #pragma unroll
    for (int mf = 0; mf < 4; ++mf) {
        #pragma unroll
        for (int r = 0; r < 16; ++r) {
            const int srow = sbase + mf * 32 + (r & 3) + 8 * (r >> 2);
            float kv = accK[mf][r] + bK;
            float vv = accV[mf][r] + bV;
            float pk = __shfl_xor(kv, 1);
            float pv = __shfl_xor(vv, 1);
            float kr = kv, vr = vv;
            if (rot) {
                float sn, cs;
                __sincosf((float)srow * invf, &sn, &cs);
                float tt = sgn * sn;
                kr = kv * cs + pk * tt;
                vr = vv * cs + pv * tt;
            }
            colsum += __cosf(kr) * __cosf(vr);
        }
    }
    colsum += __shfl_xor(colsum, 32);
    if (lane < 32)
        atomicAdd(&A[batch * 2048 + c], colsum);
}

// ---------------- Kernel 4: out = (0.5*A + 0.5) * X --------------------
__global__ void scale_out_kernel(const float* __restrict__ X,
                                 const float* __restrict__ A,
                                 float* __restrict__ out, int n4) {
    int gid = blockIdx.x * blockDim.x + threadIdx.x;
    int stride = gridDim.x * blockDim.x;
    for (int i = gid; i < n4; i += stride) {
        int e0 = i * 4;
        int b  = e0 >> 23;        // S*D = 2^23
        int d  = e0 & 2047;
        float4 a4 = *(const float4*)(A + b * 2048 + d);
        float4 x4 = ((const float4*)X)[i];
        float4 o;
        o.x = (0.5f * a4.x + 0.5f) * x4.x;
        o.y = (0.5f * a4.y + 0.5f) * x4.y;
        o.z = (0.5f * a4.z + 0.5f) * x4.z;
        o.w = (0.5f * a4.w + 0.5f) * x4.w;
        ((float4*)out)[i] = o;
    }
}

extern "C" void kernel_launch(void* const* d_in, const int* in_sizes, int n_in,
                              void* d_out, int out_size, void* d_ws, size_t ws_size,
                              hipStream_t stream) {
    const float* X    = (const float*)d_in[0];   // [4][4096][2048]
    const float* W    = (const float*)d_in[1];   // [2048][4096]
    const float* bias = (const float*)d_in[2];   // [4096]
    float* out = (float*)d_out;

    const size_t szA  = 32768;                        // 4*2048*4 (padded)
    const size_t szWf = (size_t)4096 * 2048;          // 8.4 MB fp8
    const size_t szXf = (size_t)16384 * 2048;         // 33.5 MB fp8

    char* ws = (char*)d_ws;
    float* A = (float*)ws;                            // assume ws >= 32 KB
    unsigned char* Wf;
    unsigned char* Xf;
    if (ws_size >= szA + szWf + szXf) {
        Wf = (unsigned char*)(ws + szA);
        Xf = (unsigned char*)(ws + szA + szWf);
    } else if (ws_size >= szA + szWf) {
        Wf = (unsigned char*)(ws + szA);
        Xf = (unsigned char*)d_out;                   // scratch; rewritten by kernel 4
    } else {
        Xf = (unsigned char*)d_out;
        Wf = (unsigned char*)d_out + szXf;            // 42 MB <= 134 MB
    }

    prep_x_kernel<<<8192, 256, 0, stream>>>(X, Xf, A);
    prep_w_kernel<<<dim3(64, 32), 256, 0, stream>>>(W, Wf);
    gemm_acos_kernel<<<2048, 256, 0, stream>>>(Xf, Wf, bias, A);
    scale_out_kernel<<<2048, 256, 0, stream>>>(X, A, out, 16384 * 2048 / 4);
}

// Round 14
// 232.078 us; speedup vs baseline: 14.6013x; 1.0253x over previous
//
#include <hip/hip_runtime.h>
#include <hip/hip_bf16.h>

typedef __attribute__((ext_vector_type(4)))  int   i32x4;
typedef __attribute__((ext_vector_type(8)))  int   i32x8;
typedef __attribute__((ext_vector_type(16))) float f32x16;

#define NEG_L2K (-0.025952563241307517f)  // -log2(10000)/512

#define VMW(N) asm volatile("s_waitcnt vmcnt(" #N ")" ::: "memory")
#define SCHB() __builtin_amdgcn_sched_barrier(0)
#define SBAR() __builtin_amdgcn_s_barrier()

#define AS1 __attribute__((address_space(1)))
#define AS3 __attribute__((address_space(3)))

__device__ __forceinline__ unsigned int pk4_fp8(float a, float b, float c, float d) {
    unsigned int v = __builtin_amdgcn_cvt_pk_fp8_f32(a, b, 0, false);
    v = __builtin_amdgcn_cvt_pk_fp8_f32(c, d, v, true);
    return v;
}

// ---------------- Kernel 1: X fp32 -> fp8, fragment-major, BM=128 tiles ----
// Tile (mtile,kt) = 8192 B at (mtile*32+kt)*8192.  Chunk s*64+lane (16 B):
// s = mf*2+rd; bytes = fp8(X[mtile*128+mf*32+(lane&31)][kt*64+(lane>>5)*32+rd*16 ..+16])
__global__ __launch_bounds__(256) void prep_x_kernel(const float* __restrict__ X,
                                                     unsigned char* __restrict__ Xf,
                                                     float* __restrict__ A) {
    int g = blockIdx.x * 256 + threadIdx.x;   // 0 .. 2^21-1
    if (g < 8192) A[g] = 0.0f;
    int tileid = g >> 9;       // 0..4095
    int mtile  = tileid >> 5;  // 0..127
    int kt     = tileid & 31;
    int c      = g & 511;
    int s      = c >> 6;       // 0..7 = mf*2+rd
    int lane   = c & 63;
    int row  = mtile * 128 + (s >> 1) * 32 + (lane & 31);
    int kcol = kt * 64 + (lane >> 5) * 32 + (s & 1) * 16;
    const float* src = X + (size_t)row * 2048 + kcol;
    float4 f0 = *(const float4*)(src);
    float4 f1 = *(const float4*)(src + 4);
    float4 f2 = *(const float4*)(src + 8);
    float4 f3 = *(const float4*)(src + 12);
    uint4 o;
    o.x = pk4_fp8(f0.x, f0.y, f0.z, f0.w);
    o.y = pk4_fp8(f1.x, f1.y, f1.z, f1.w);
    o.z = pk4_fp8(f2.x, f2.y, f2.z, f2.w);
    o.w = pk4_fp8(f3.x, f3.y, f3.z, f3.w);
    *(uint4*)(Xf + (size_t)g * 16) = o;
}

// ---------------- Kernel 2: W fp32 -> fp8 (x16 pre-scale) frag-major -------
// (verified R7 — unchanged)  Out tile (ntile,kt,KV) = 8 KB at
// ((ntile*32+kt)*2+KV)*8192; chunk (wc*2+rd)*64+lane holds
// W[kt*64+(lane>>5)*32+rd*16 ..+16][ntile*128+wc*32+(lane&31)]*16
__global__ __launch_bounds__(256) void prep_w_kernel(const float* __restrict__ W,
                                                     unsigned char* __restrict__ Wf) {
    __shared__ unsigned char t[64][72];
    int f0 = blockIdx.x * 64;   // along 4096 (f)
    int k0 = blockIdx.y * 64;   // along 2048 (k)
    int tx = threadIdx.x & 63;
    int ty = threadIdx.x >> 6;
    for (int r = ty; r < 64; r += 4) {
        float w = W[(size_t)(k0 + r) * 4096 + f0 + tx] * 16.0f;
        t[r][tx] = (unsigned char)(__builtin_amdgcn_cvt_pk_fp8_f32(w, w, 0, false) & 0xFF);
    }
    __syncthreads();
    int c   = threadIdx.x;
    int il  = c & 31;
    int lh  = (c >> 5) & 1;
    int rd  = (c >> 6) & 1;
    int wcl = c >> 7;
    int col_l = wcl * 32 + il;          // 0..63 within block
    int kl    = lh * 32 + rd * 16;
    int fh    = f0 & 2047;
    int KV    = f0 >> 11;
    int ntile = fh >> 7;
    int wcg   = ((fh >> 5) & 2) + wcl;
    union { unsigned char b[16]; uint4 v; } ob;
    #pragma unroll
    for (int b = 0; b < 16; ++b) ob.b[b] = t[kl + b][col_l];
    size_t base = ((((size_t)ntile * 32 + blockIdx.y) * 2 + KV) << 13)
                + (size_t)(((wcg * 2 + rd) * 64 + lh * 32 + il) << 4);
    *(uint4*)(Wf + base) = ob.v;
}

// ---------------- Kernel 3: fused fp8 GEMM + rotary + cos*cos + reduce ----
// MX-fp8 mfma_scale 32x32x64.  4 waves/block, BM=128, 2 blocks/CU so two
// independent barrier schedules overlap per CU (LDS-read phase of one block
// hides under MFMA clusters of the other).  VMW(6) + 2 barriers per K-step.
// Measured best of 7 schedule variants (R8): 158 us, 1740 TF.
__global__ __launch_bounds__(256, 2) void gemm_acos_kernel(
    const unsigned char* __restrict__ Xf,
    const unsigned char* __restrict__ Wf,
    const float* __restrict__ bias,
    float* __restrict__ A)
{
    __shared__ __align__(16) unsigned char Als[2][8192];
    __shared__ __align__(16) unsigned char Kls[2][8192];
    __shared__ __align__(16) unsigned char Vls[2][8192];

    const int tid  = threadIdx.x;
    const int lane = tid & 63;
    const int wc   = tid >> 6;    // 0..3  col quarter (32 cols)
    const int l31  = lane & 31;
    const int lh   = lane >> 5;

    // T1: bijective XCD swizzle, grid 2048 = 128 mtiles x 16 ntiles
    const int orig  = blockIdx.x;
    const int wg    = (orig & 7) * 256 + (orig >> 3);
    const int mtile = wg & 127;
    const int ntile = wg >> 7;
    const int row0  = mtile * 128;
    const int n0    = ntile * 128;

    const unsigned char* XfT = Xf + ((size_t)(mtile * 32) << 13);
    const unsigned char* WfT = Wf + ((size_t)(ntile * 32) << 14);

    f32x16 accK[4] = {};
    f32x16 accV[4] = {};

    const int abase = lane * 16;                 // + mf*2048 + rd*1024
    const int bbase = (wc * 128 + lane) * 16;    // + rd*1024

    // stage one K-tile (A 8 KB, K 8 KB, V 8 KB) -> 6 loads/thread
    #define STAGE(T, NB)                                                                    \
        do {                                                                                \
            const unsigned char* ga = XfT + ((size_t)(T) << 13);                            \
            const unsigned char* gw = WfT + ((size_t)(T) << 14);                            \
            __builtin_amdgcn_global_load_lds((const AS1 void*)(ga + tid * 16),              \
                (AS3 void*)(Als[NB] + tid * 16), 16, 0, 0);                                 \
            __builtin_amdgcn_global_load_lds((const AS1 void*)(ga + 4096 + tid * 16),       \
                (AS3 void*)(Als[NB] + 4096 + tid * 16), 16, 0, 0);                          \
            __builtin_amdgcn_global_load_lds((const AS1 void*)(gw + tid * 16),              \
                (AS3 void*)(Kls[NB] + tid * 16), 16, 0, 0);                                 \
            __builtin_amdgcn_global_load_lds((const AS1 void*)(gw + 4096 + tid * 16),       \
                (AS3 void*)(Kls[NB] + 4096 + tid * 16), 16, 0, 0);                          \
            __builtin_amdgcn_global_load_lds((const AS1 void*)(gw + 8192 + tid * 16),       \
                (AS3 void*)(Vls[NB] + tid * 16), 16, 0, 0);                                 \
            __builtin_amdgcn_global_load_lds((const AS1 void*)(gw + 12288 + tid * 16),      \
                (AS3 void*)(Vls[NB] + 4096 + tid * 16), 16, 0, 0);                          \
        } while (0)

    STAGE(0, 0);

    #pragma unroll 1
    for (int it = 0; it < 16; ++it) {
        #pragma unroll
        for (int sub = 0; sub < 2; ++sub) {
            const int t = it * 2 + sub;
            const bool last = (t == 31);
            const unsigned char* As = Als[sub];
            const unsigned char* Ks = Kls[sub];
            const unsigned char* Vs = Vls[sub];

            if (!last) { STAGE(t + 1, sub ^ 1); VMW(6); } else { VMW(0); }
            SCHB();
            SBAR();

            i32x8 a8[4], bk8, bv8;
            #pragma unroll
            for (int mf = 0; mf < 4; ++mf) {
                i32x4 lo = *(const i32x4*)(As + abase + mf * 2048);
                i32x4 hi = *(const i32x4*)(As + abase + mf * 2048 + 1024);
                a8[mf] = __builtin_shufflevector(lo, hi, 0, 1, 2, 3, 4, 5, 6, 7);
            }
            {
                i32x4 lo = *(const i32x4*)(Ks + bbase);
                i32x4 hi = *(const i32x4*)(Ks + bbase + 1024);
                bk8 = __builtin_shufflevector(lo, hi, 0, 1, 2, 3, 4, 5, 6, 7);
            }
            __builtin_amdgcn_s_setprio(1);
            #pragma unroll
            for (int mf = 0; mf < 4; ++mf)
                accK[mf] = __builtin_amdgcn_mfma_scale_f32_32x32x64_f8f6f4(
                    a8[mf], bk8, accK[mf], 0, 0, 0, 0x7F7F7F7F, 0, 0x7B7B7B7B);
            __builtin_amdgcn_s_setprio(0);

            {
                i32x4 lo = *(const i32x4*)(Vs + bbase);
                i32x4 hi = *(const i32x4*)(Vs + bbase + 1024);
                bv8 = __builtin_shufflevector(lo, hi, 0, 1, 2, 3, 4, 5, 6, 7);
            }
            __builtin_amdgcn_s_setprio(1);
            #pragma unroll
            for (int mf = 0; mf < 4; ++mf)
                accV[mf] = __builtin_amdgcn_mfma_scale_f32_32x32x64_f8f6f4(
                    a8[mf], bv8, accV[mf], 0, 0, 0, 0x7F7F7F7F, 0, 0x7B7B7B7B);
            __builtin_amdgcn_s_setprio(0);
            SBAR();
        }
    }

    // ---- epilogue: bias, rotary, cos*cos, reduce over rows, atomicAdd
    // C/D (32x32): col = lane&31, row = (reg&3) + 8*(reg>>2) + 4*lh
    const int batch = row0 >> 12;
    const int c     = n0 + wc * 32 + l31;
    const float bK  = bias[c];
    const float bV  = bias[c + 2048];
    const bool rot  = (c < 1024);
    const float invf = exp2f((float)(c >> 1) * NEG_L2K);
    const float sgn  = (c & 1) ? 1.0f : -1.0f;
    const int sbase  = (row0 & 4095) + 4 * lh;

    float colsum = 0.0f;
    #pragma unroll
    for (int mf = 0; mf < 4; ++mf) {
        #pragma unroll
        for (int r = 0; r < 16; ++r) {
            const int srow = sbase + mf * 32 + (r & 3) + 8 * (r >> 2);
            float kv = accK[mf][r] + bK;
            float vv = accV[mf][r] + bV;
            float pk = __shfl_xor(kv, 1);
            float pv = __shfl_xor(vv, 1);
            float kr = kv, vr = vv;
            if (rot) {
                float sn, cs;
                __sincosf((float)srow * invf, &sn, &cs);
                float tt = sgn * sn;
                kr = kv * cs + pk * tt;
                vr = vv * cs + pv * tt;
            }
            colsum += __cosf(kr) * __cosf(vr);
        }
    }
    colsum += __shfl_xor(colsum, 32);
    if (lane < 32)
        atomicAdd(&A[batch * 2048 + c], colsum);
}

// ---------------- Kernel 4: out = (0.5*A + 0.5) * X --------------------
__global__ void scale_out_kernel(const float* __restrict__ X,
                                 const float* __restrict__ A,
                                 float* __restrict__ out, int n4) {
    int gid = blockIdx.x * blockDim.x + threadIdx.x;
    int stride = gridDim.x * blockDim.x;
    for (int i = gid; i < n4; i += stride) {
        int e0 = i * 4;
        int b  = e0 >> 23;        // S*D = 2^23
        int d  = e0 & 2047;
        float4 a4 = *(const float4*)(A + b * 2048 + d);
        float4 x4 = ((const float4*)X)[i];
        float4 o;
        o.x = (0.5f * a4.x + 0.5f) * x4.x;
        o.y = (0.5f * a4.y + 0.5f) * x4.y;
        o.z = (0.5f * a4.z + 0.5f) * x4.z;
        o.w = (0.5f * a4.w + 0.5f) * x4.w;
        ((float4*)out)[i] = o;
    }
}

extern "C" void kernel_launch(void* const* d_in, const int* in_sizes, int n_in,
                              void* d_out, int out_size, void* d_ws, size_t ws_size,
                              hipStream_t stream) {
    const float* X    = (const float*)d_in[0];   // [4][4096][2048]
    const float* W    = (const float*)d_in[1];   // [2048][4096]
    const float* bias = (const float*)d_in[2];   // [4096]
    float* out = (float*)d_out;

    const size_t szA  = 32768;                        // 4*2048*4 (padded)
    const size_t szWf = (size_t)4096 * 2048;          // 8.4 MB fp8
    const size_t szXf = (size_t)16384 * 2048;         // 33.5 MB fp8

    char* ws = (char*)d_ws;
    float* A = (float*)ws;                            // assume ws >= 32 KB
    unsigned char* Wf;
    unsigned char* Xf;
    if (ws_size >= szA + szWf + szXf) {
        Wf = (unsigned char*)(ws + szA);
        Xf = (unsigned char*)(ws + szA + szWf);
    } else if (ws_size >= szA + szWf) {
        Wf = (unsigned char*)(ws + szA);
        Xf = (unsigned char*)d_out;                   // scratch; rewritten by kernel 4
    } else {
        Xf = (unsigned char*)d_out;
        Wf = (unsigned char*)d_out + szXf;            // 42 MB <= 134 MB
    }

    prep_x_kernel<<<8192, 256, 0, stream>>>(X, Xf, A);
    prep_w_kernel<<<dim3(64, 32), 256, 0, stream>>>(W, Wf);
    gemm_acos_kernel<<<2048, 256, 0, stream>>>(Xf, Wf, bias, A);
    scale_out_kernel<<<2048, 256, 0, stream>>>(X, A, out, 16384 * 2048 / 4);
}